// Round 2
// baseline (1206.311 us; speedup 1.0000x reference)
//
#include <hip/hip_runtime.h>
#include <math.h>

#define B_  4
#define L_  8192
#define D_  512
#define TT  16
#define BL_ (B_*L_)

// ---------------------------------------------------------------------------
// Weight fusion: grouped conv (128 groups, I=4, O=2, K=3) folded into the
// bscore GEMM.  pf[o][l] = sum_{i,k} x[l+k-1][4g+i] * Wc[o][i][k]  (g=o>>1)
// a2[l][j] = x[l]@Wb1[:512] + pf[l]@Wb1[512:] + (bc@Wb1[512:])
//          = x[l-1]@F0 + x[l]@F1 + x[l+1]@F2          (+ bias folded to bb1e)
// F_k[c][j] = Wc[2g][c&3][k]*Wb1[512+2g][j] + Wc[2g+1][c&3][k]*Wb1[512+2g+1][j]
// F1 additionally += Wb1[c][j].
// ---------------------------------------------------------------------------
__global__ __launch_bounds__(256) void k_fuse(
    const float* __restrict__ Wc, const float* __restrict__ Wb1,
    float* __restrict__ F)
{
  const int idx = blockIdx.x * 256 + threadIdx.x;   // 65536 = 512*128
  const int c = idx >> 7;
  const int j = idx & 127;
  const int g = c >> 2;
  const int i = c & 3;
  const float wbA = Wb1[(size_t)(512 + 2 * g) * 128 + j];
  const float wbB = Wb1[(size_t)(512 + 2 * g + 1) * 128 + j];
  const float* wcA = Wc + (size_t)(2 * g) * 12 + i * 3;
  const float* wcB = Wc + (size_t)(2 * g + 1) * 12 + i * 3;
#pragma unroll
  for (int k = 0; k < 3; ++k) {
    float v = wcA[k] * wbA + wcB[k] * wbB;
    if (k == 1) v += Wb1[(size_t)c * 128 + j];
    F[(size_t)k * (512 * 128) + idx] = v;
  }
}

__global__ __launch_bounds__(128) void k_biasfuse(
    const float* __restrict__ bc, const float* __restrict__ Wb1,
    const float* __restrict__ bb1, float* __restrict__ bb1e)
{
  const int j = threadIdx.x;
  float acc = bb1[j];
  for (int o = 0; o < 256; ++o)
    acc = fmaf(bc[o], Wb1[(size_t)(512 + o) * 128 + j], acc);
  bb1e[j] = acc;
}

// ---------------------------------------------------------------------------
// Signal: content = sigmoid(relu(x@W1+b1)@W2+b2)
//         bscore  = sigmoid(relu(x[l-1]@F0 + x[l]@F1 + x[l+1]@F2 + bb1e)@Wb2+bb2)
//         signal  = content*(1-bscore)*mask
// One block = 16 tokens; thread = (jq,tq) -> 4 j-cols x 2 tokens.
// 4 independent weight streams per K-iter, 32 FMA per K-iter.
// ---------------------------------------------------------------------------
__global__ __launch_bounds__(256, 4) void k_signal(
    const float* __restrict__ x, const float* __restrict__ mask,
    const float* __restrict__ W1, const float* __restrict__ b1,
    const float* __restrict__ W2, const float* __restrict__ b2,
    const float* __restrict__ F,  const float* __restrict__ bb1e,
    const float* __restrict__ Wb2, const float* __restrict__ bb2,
    float* __restrict__ signal)
{
  __shared__ float xs[TT + 2][D_];      // rows l0-1 .. l0+TT (zero padded)
  // part1/part2 alias xs rows 0/1 after the GEMM (extra barrier below)
  float (*part1)[32] = reinterpret_cast<float(*)[32]>(&xs[0][0]);
  float (*part2)[32] = reinterpret_cast<float(*)[32]>(&xs[2][0]);

  const int tile = blockIdx.x;          // 2048 tiles, 512 per batch row
  const int b = tile >> 9;
  const int l0 = (tile & 511) * TT;
  const int t = threadIdx.x;
  const float* xb = x + (size_t)b * L_ * D_;

  for (int i = t; i < (TT + 2) * (D_ / 4); i += 256) {
    int r  = i >> 7;                    // D_/4 == 128
    int c4 = i & 127;
    int l  = l0 - 1 + r;
    float4 v = make_float4(0.f, 0.f, 0.f, 0.f);
    if (l >= 0 && l < L_)
      v = reinterpret_cast<const float4*>(xb + (size_t)l * D_)[c4];
    reinterpret_cast<float4*>(&xs[r][0])[c4] = v;
  }
  __syncthreads();

  const int jq   = t & 31;
  const int tq   = t >> 5;
  const int j0   = jq << 2;
  const int tok0 = tq << 1;             // token pair; xs row of token tok0 is tok0+1

  const float* F0 = F;
  const float* F1 = F + 512 * 128;
  const float* F2 = F + 2 * 512 * 128;

  float a1[2][4] = {{0,0,0,0},{0,0,0,0}};
  float a2[2][4] = {{0,0,0,0},{0,0,0,0}};

#pragma unroll 2
  for (int k = 0; k < D_; ++k) {
    const float4 w1 = *reinterpret_cast<const float4*>(W1 + (k << 7) + j0);
    const float4 f0 = *reinterpret_cast<const float4*>(F0 + (k << 7) + j0);
    const float4 f1 = *reinterpret_cast<const float4*>(F1 + (k << 7) + j0);
    const float4 f2 = *reinterpret_cast<const float4*>(F2 + (k << 7) + j0);
    const float x0 = xs[tok0 + 0][k];   // row l0+tok0-1
    const float x1 = xs[tok0 + 1][k];   // row l0+tok0
    const float x2 = xs[tok0 + 2][k];   // row l0+tok0+1
    const float x3 = xs[tok0 + 3][k];   // row l0+tok0+2

    a1[0][0] = fmaf(x1, w1.x, a1[0][0]); a1[0][1] = fmaf(x1, w1.y, a1[0][1]);
    a1[0][2] = fmaf(x1, w1.z, a1[0][2]); a1[0][3] = fmaf(x1, w1.w, a1[0][3]);
    a1[1][0] = fmaf(x2, w1.x, a1[1][0]); a1[1][1] = fmaf(x2, w1.y, a1[1][1]);
    a1[1][2] = fmaf(x2, w1.z, a1[1][2]); a1[1][3] = fmaf(x2, w1.w, a1[1][3]);

    a2[0][0] = fmaf(x0, f0.x, a2[0][0]); a2[0][1] = fmaf(x0, f0.y, a2[0][1]);
    a2[0][2] = fmaf(x0, f0.z, a2[0][2]); a2[0][3] = fmaf(x0, f0.w, a2[0][3]);
    a2[0][0] = fmaf(x1, f1.x, a2[0][0]); a2[0][1] = fmaf(x1, f1.y, a2[0][1]);
    a2[0][2] = fmaf(x1, f1.z, a2[0][2]); a2[0][3] = fmaf(x1, f1.w, a2[0][3]);
    a2[0][0] = fmaf(x2, f2.x, a2[0][0]); a2[0][1] = fmaf(x2, f2.y, a2[0][1]);
    a2[0][2] = fmaf(x2, f2.z, a2[0][2]); a2[0][3] = fmaf(x2, f2.w, a2[0][3]);

    a2[1][0] = fmaf(x1, f0.x, a2[1][0]); a2[1][1] = fmaf(x1, f0.y, a2[1][1]);
    a2[1][2] = fmaf(x1, f0.z, a2[1][2]); a2[1][3] = fmaf(x1, f0.w, a2[1][3]);
    a2[1][0] = fmaf(x2, f1.x, a2[1][0]); a2[1][1] = fmaf(x2, f1.y, a2[1][1]);
    a2[1][2] = fmaf(x2, f1.z, a2[1][2]); a2[1][3] = fmaf(x2, f1.w, a2[1][3]);
    a2[1][0] = fmaf(x3, f2.x, a2[1][0]); a2[1][1] = fmaf(x3, f2.y, a2[1][1]);
    a2[1][2] = fmaf(x3, f2.z, a2[1][2]); a2[1][3] = fmaf(x3, f2.w, a2[1][3]);
  }

  __syncthreads();   // GEMM done reading xs; parts alias xs below

  {
    float w2v[4], wv2[4], b1v[4], bbv[4];
#pragma unroll
    for (int jj = 0; jj < 4; ++jj) {
      w2v[jj] = W2[j0 + jj];  wv2[jj] = Wb2[j0 + jj];
      b1v[jj] = b1[j0 + jj];  bbv[jj] = bb1e[j0 + jj];
    }
#pragma unroll
    for (int i = 0; i < 2; ++i) {
      float p1s = 0.f, p2s = 0.f;
#pragma unroll
      for (int jj = 0; jj < 4; ++jj) {
        float h1 = a1[i][jj] + b1v[jj];
        if (h1 > 0.f) p1s = fmaf(h1, w2v[jj], p1s);
        float h2 = a2[i][jj] + bbv[jj];
        if (h2 > 0.f) p2s = fmaf(h2, wv2[jj], p2s);
      }
      part1[tok0 + i][jq] = p1s;
      part2[tok0 + i][jq] = p2s;
    }
  }
  __syncthreads();

  if (t < TT) {
    float z1 = b2[0], z2 = bb2[0];
    for (int q = 0; q < 32; ++q) { z1 += part1[t][q]; z2 += part2[t][q]; }
    const float content = 1.f / (1.f + expf(-z1));
    const float bscore  = 1.f / (1.f + expf(-z2));
    const int gi = b * L_ + l0 + t;
    signal[gi] = content * (1.f - bscore) * mask[gi];
  }
}

// ---------------------------------------------------------------------------
// Exact 0.7-quantile per row via MSB-first radix select on monotonic keys.
// ---------------------------------------------------------------------------
__global__ __launch_bounds__(256) void k_quantile(const float* __restrict__ signal,
                                                  float* __restrict__ thr)
{
  __shared__ unsigned int bins[256];
  __shared__ unsigned int sh_prefix;
  __shared__ int sh_rank;
  __shared__ unsigned int keys_out[2];
  const int b = blockIdx.x, t = threadIdx.x;
  const float* s = signal + b * L_;
  const int rank0 = 5733;   // floor(0.7*(L-1)) for L=8192

  for (int which = 0; which < 2; ++which) {
    if (t == 0) { sh_prefix = 0u; sh_rank = rank0 + which; }
    __syncthreads();
    for (int round = 0; round < 4; ++round) {
      bins[t] = 0u;
      __syncthreads();
      const unsigned int pre = sh_prefix;
      const int shift = 24 - 8 * round;
      for (int i = t; i < L_; i += 256) {
        unsigned int u = __float_as_uint(s[i]);
        unsigned int key = (u & 0x80000000u) ? ~u : (u | 0x80000000u);
        if (round == 0) {
          atomicAdd(&bins[key >> 24], 1u);
        } else if ((key >> (shift + 8)) == pre) {
          atomicAdd(&bins[(key >> shift) & 255u], 1u);
        }
      }
      __syncthreads();
      if (t == 0) {
        int r = sh_rank;
        unsigned int c = 0;
        while (r >= (int)bins[c]) { r -= (int)bins[c]; ++c; }
        sh_rank = r;
        sh_prefix = (pre << 8) | c;
      }
      __syncthreads();
    }
    if (t == 0) keys_out[which] = sh_prefix;
    __syncthreads();
  }
  if (t == 0) {
    unsigned int k0 = keys_out[0], k1 = keys_out[1];
    unsigned int u0 = (k0 & 0x80000000u) ? (k0 & 0x7fffffffu) : ~k0;
    unsigned int u1 = (k1 & 0x80000000u) ? (k1 & 0x7fffffffu) : ~k1;
    double v0 = (double)__uint_as_float(u0);
    double v1 = (double)__uint_as_float(u1);
    double g = 0.7 * (double)(L_ - 1) - (double)rank0;
    thr[b] = (float)(v0 + g * (v1 - v0));
  }
}

// ---------------------------------------------------------------------------
// Greedy enforce: wave-parallel chain walk over candidate bits held in
// 2 registers/lane of wave 0 (ballot+shfl+ffs per step, no LDS round-trips).
// ---------------------------------------------------------------------------
__global__ __launch_bounds__(256) void k_enforce(
    const float* __restrict__ signal, const float* __restrict__ thr_arr,
    int* __restrict__ starts, int* __restrict__ nlast, float* __restrict__ bounds)
{
  __shared__ unsigned long long cw[L_ / 64];   // 128 words
  __shared__ unsigned char nb[L_];
  __shared__ int tsum[256];
  __shared__ int offs[257];
  const int b = blockIdx.x, t = threadIdx.x;
  const float thr = thr_arr[b];
  const float* s = signal + b * L_;
  const int wave = t >> 6, lane = t & 63;

  // build candidate bitmap via coalesced loads + ballot (4 waves x 32 iters)
  for (int i = 0; i < L_ / 256; ++i) {
    unsigned long long m = __ballot(s[i * 256 + t] < thr);
    if (lane == 0) cw[i * 4 + wave] = m;
  }
  {
    const int base = t * (L_ / 256);
    for (int i = 0; i < L_ / 256; ++i) nb[base + i] = 0;
  }
  __syncthreads();
  if (t == 0) cw[L_ / 64 - 1] |= (1ull << 63);   // forced candidate at L-1
  __syncthreads();

  if (t < 64) {
    const unsigned long long w0 = cw[lane];
    const unsigned long long w1 = cw[64 + lane];
    int st = 0;
    for (;;) {
      const int from = st + 4;
      if (from >= L_) break;
      const int r0 = from - (lane << 6);
      unsigned long long m0 = (r0 <= 0) ? w0 : (r0 >= 64 ? 0ull : (w0 & (~0ull << r0)));
      const int r1 = from - ((64 + lane) << 6);
      unsigned long long m1 = (r1 <= 0) ? w1 : (r1 >= 64 ? 0ull : (w1 & (~0ull << r1)));
      const unsigned long long b0 = __ballot(m0 != 0ull);
      int p;
      if (b0 != 0ull) {
        const int wsel = __ffsll(b0) - 1;
        const unsigned long long mw = __shfl(m0, wsel, 64);
        p = (wsel << 6) + __ffsll(mw) - 1;
      } else {
        const unsigned long long b1m = __ballot(m1 != 0ull);
        if (b1m == 0ull) break;
        const int wsel = __ffsll(b1m) - 1;
        const unsigned long long mw = __shfl(m1, wsel, 64);
        p = ((64 + wsel) << 6) + __ffsll(mw) - 1;
      }
      const int ps = p - st;
      if (lane == 0) nb[p] = 1;
      const int k = (ps + 15) >> 4;
      if (k > 1) {
        int sz = ps / k; if (sz < 1) sz = 1;
        for (int j = 1 + lane; j < k; j += 64) nb[st + j * sz] = 1;
      }
      st = p;
    }
  }
  __syncthreads();

  const int base = t * 32;
  int ls = 0;
  for (int i = 0; i < 32; ++i) ls += nb[base + i];
  tsum[t] = ls;
  __syncthreads();
  if (t == 0) {
    int r = 0;
    for (int i = 0; i < 256; ++i) { offs[i] = r; r += tsum[i]; }
    offs[256] = r;
  }
  __syncthreads();

  int run = offs[t];
  for (int i = 0; i < 32; ++i) {
    run += nb[base + i];
    if (nb[base + i]) starts[b * L_ + run] = base + i;
  }
  if (t == 0) { starts[b * L_ + 0] = 0; nlast[b] = offs[256]; }
  const int total = offs[256];
  for (int i = t; i < L_; i += 256) {
    bounds[b * L_ + i] = (i >= 1 && i <= total) ? 1.0f : 0.0f;
  }
}

// ---------------------------------------------------------------------------
// e[tok] = sum_d (x*mask)^2  — one wave per token, tree reduce.
// ---------------------------------------------------------------------------
__global__ __launch_bounds__(256) void k_e(const float* __restrict__ x,
                                           const float* __restrict__ mask,
                                           float* __restrict__ e)
{
  const int wave = threadIdx.x >> 6, lane = threadIdx.x & 63;
  const int tok = (blockIdx.x << 2) + wave;
  const float m = mask[tok];
  const float* xr = x + (size_t)tok * D_ + (lane << 3);
  const float4 v0 = reinterpret_cast<const float4*>(xr)[0];
  const float4 v1 = reinterpret_cast<const float4*>(xr)[1];
  float acc = 0.f, q;
  q = v0.x * m; acc = fmaf(q, q, acc);
  q = v0.y * m; acc = fmaf(q, q, acc);
  q = v0.z * m; acc = fmaf(q, q, acc);
  q = v0.w * m; acc = fmaf(q, q, acc);
  q = v1.x * m; acc = fmaf(q, q, acc);
  q = v1.y * m; acc = fmaf(q, q, acc);
  q = v1.z * m; acc = fmaf(q, q, acc);
  q = v1.w * m; acc = fmaf(q, q, acc);
#pragma unroll
  for (int off = 32; off > 0; off >>= 1) acc += __shfl_down(acc, off, 64);
  if (lane == 0) e[tok] = acc;
}

// ---------------------------------------------------------------------------
// Segment softmax-merge: one wave per segment id (contiguous token range).
// ---------------------------------------------------------------------------
__global__ __launch_bounds__(64) void k_merge(const float* __restrict__ x,
    const float* __restrict__ mask, const float* __restrict__ e,
    const int* __restrict__ starts, const int* __restrict__ nlast,
    float* __restrict__ merged)
{
  const int idx = blockIdx.x;
  const int b   = idx >> 13;            // L_ == 8192
  const int sid = idx & (L_ - 1);
  const int n = nlast[b];
  if (sid > n) return;                  // rows pre-zeroed
  const int t0 = starts[b * L_ + sid];
  const int t1 = (sid < n) ? starts[b * L_ + sid + 1] : L_;
  const float* eb = e + b * L_;

  float mx = -INFINITY;
  for (int p = t0; p < t1; ++p) mx = fmaxf(mx, eb[p]);
  float den = 0.f;
  for (int p = t0; p < t1; ++p) den += expf(eb[p] - mx);

  const int lane = threadIdx.x;
  const int c0 = lane << 3;
  float acc[8] = {0,0,0,0,0,0,0,0};
  for (int p = t0; p < t1; ++p) {
    const float wn = expf(eb[p] - mx) / den;
    const float sc = wn * mask[b * L_ + p];
    const float* xr = x + ((size_t)(b * L_ + p)) * D_ + c0;
    const float4 u0 = reinterpret_cast<const float4*>(xr)[0];
    const float4 u1 = reinterpret_cast<const float4*>(xr)[1];
    acc[0] = fmaf(sc, u0.x, acc[0]); acc[1] = fmaf(sc, u0.y, acc[1]);
    acc[2] = fmaf(sc, u0.z, acc[2]); acc[3] = fmaf(sc, u0.w, acc[3]);
    acc[4] = fmaf(sc, u1.x, acc[4]); acc[5] = fmaf(sc, u1.y, acc[5]);
    acc[6] = fmaf(sc, u1.z, acc[6]); acc[7] = fmaf(sc, u1.w, acc[7]);
  }
  float* o = merged + (size_t)(b * L_ + sid) * D_ + c0;
  reinterpret_cast<float4*>(o)[0] = make_float4(acc[0], acc[1], acc[2], acc[3]);
  reinterpret_cast<float4*>(o)[1] = make_float4(acc[4], acc[5], acc[6], acc[7]);
}

// ---------------------------------------------------------------------------
extern "C" void kernel_launch(void* const* d_in, const int* in_sizes, int n_in,
                              void* d_out, int out_size, void* d_ws, size_t ws_size,
                              hipStream_t stream) {
  (void)in_sizes; (void)n_in; (void)out_size; (void)ws_size;
  const float* x    = (const float*)d_in[0];
  const float* mask = (const float*)d_in[1];
  const float* W1   = (const float*)d_in[2];
  const float* b1   = (const float*)d_in[3];
  const float* W2   = (const float*)d_in[4];
  const float* b2   = (const float*)d_in[5];
  const float* Wc   = (const float*)d_in[6];
  const float* bc   = (const float*)d_in[7];
  const float* Wb1  = (const float*)d_in[8];
  const float* bb1  = (const float*)d_in[9];
  const float* Wb2  = (const float*)d_in[10];
  const float* bb2  = (const float*)d_in[11];

  float* merged = (float*)d_out;
  float* bounds = (float*)d_out + (size_t)BL_ * D_;

  char* ws = (char*)d_ws;
  float* signal = (float*)(ws);                          // 128 KB
  float* e      = (float*)(ws + (size_t)BL_ * 4);        // 128 KB
  int*   starts = (int*)  (ws + (size_t)BL_ * 8);        // 128 KB
  int*   nlast  = (int*)  (ws + (size_t)BL_ * 12);       // 64 B
  float* thr    = (float*)(ws + (size_t)BL_ * 12 + 64);  // 64 B
  float* F      = (float*)(ws + (size_t)524288);         // 3*256 KB
  float* bb1e   = (float*)(ws + (size_t)524288 + 786432);// 512 B

  hipMemsetAsync(merged, 0, (size_t)BL_ * D_ * sizeof(float), stream);

  k_fuse<<<256, 256, 0, stream>>>(Wc, Wb1, F);
  k_biasfuse<<<1, 128, 0, stream>>>(bc, Wb1, bb1, bb1e);
  k_signal<<<BL_ / TT, 256, 0, stream>>>(x, mask, W1, b1, W2, b2,
                                         F, bb1e, Wb2, bb2, signal);
  k_quantile<<<B_, 256, 0, stream>>>(signal, thr);
  k_enforce<<<B_, 256, 0, stream>>>(signal, thr, starts, nlast, bounds);
  k_e<<<BL_ / 4, 256, 0, stream>>>(x, mask, e);
  k_merge<<<BL_, 64, 0, stream>>>(x, mask, e, starts, nlast, merged);
}

// Round 3
// 783.501 us; speedup vs baseline: 1.5396x; 1.5396x over previous
//
#include <hip/hip_runtime.h>
#include <math.h>

#define B_  4
#define L_  8192
#define D_  512
#define BL_ (B_*L_)
#define TOK 64
#define KC  32
#define NCH (D_/KC)

// ---------------------------------------------------------------------------
// Signal: content = sigmoid(relu(x@W1+b1)@W2+b2)
//         pf      = groupedconv(x)+bc  (computed per K-chunk into LDS)
//         bscore  = sigmoid(relu([x,pf]@Wb1+bb1)@Wb2+bb2)
//         signal  = content*(1-bscore)*mask
// 64 tokens/block, K-chunked. Thread = (jq 0..31, tw 0..7) owns 8 tok x 4 j.
// 64 FMA per k-iter vs 2 global(b128)+2 LDS(b128) loads.
// ---------------------------------------------------------------------------
__global__ __launch_bounds__(256, 2) void k_signal(
    const float* __restrict__ x, const float* __restrict__ mask,
    const float* __restrict__ W1, const float* __restrict__ b1,
    const float* __restrict__ W2, const float* __restrict__ b2,
    const float* __restrict__ Wc, const float* __restrict__ bc,
    const float* __restrict__ Wb1, const float* __restrict__ bb1,
    const float* __restrict__ Wb2, const float* __restrict__ bb2,
    float* __restrict__ signal)
{
  __shared__ float xt[KC][TOK + 4];   // [k][tok]; tok 64 = l0-1, 65 = l0+64; stride 68 (272B, 16B-aligned)
  __shared__ float pf[16][TOK];       // conv out chunk [oo][tok]

  const int t   = threadIdx.x;
  const int blk = blockIdx.x;          // 512 = 4 b x 128 tiles
  const int b   = blk >> 7;
  const int l0  = (blk & 127) * TOK;
  const float* xb = x + (size_t)b * L_ * D_;

  const int jq = t & 31, tw = t >> 5;
  const int j0 = jq << 2, tok0 = tw << 3;

  float a1[8][4], a2[8][4];
#pragma unroll
  for (int i = 0; i < 8; ++i)
#pragma unroll
    for (int j = 0; j < 4; ++j) { a1[i][j] = 0.f; a2[i][j] = 0.f; }

  // conv role for this thread (fixed across chunks)
  const int oo_c   = t >> 4;           // 0..15
  const int tokq_c = t & 15;           // 0..15
  const int cb_c   = (oo_c >> 1) << 2; // relative channel base 0..28
  const int tok0c  = tokq_c << 2;

  for (int c = 0; c < NCH; ++c) {
    const int kc = c << 5;
    __syncthreads();                   // xt/pf free of previous readers

    // ---- stage x chunk (transposed) ----
#pragma unroll
    for (int rep = 0; rep < 2; ++rep) {
      const int slot = (rep << 8) + t;       // 0..511
      const int tok = slot >> 3, kk = slot & 7;
      const float4 v = *reinterpret_cast<const float4*>(
          xb + (size_t)(l0 + tok) * D_ + kc + (kk << 2));
      xt[(kk << 2) + 0][tok] = v.x; xt[(kk << 2) + 1][tok] = v.y;
      xt[(kk << 2) + 2][tok] = v.z; xt[(kk << 2) + 3][tok] = v.w;
    }
    if (t < 16) {
      const int hh = t >> 3, kk = t & 7;
      const int l = hh ? (l0 + TOK) : (l0 - 1);
      float4 v = make_float4(0.f, 0.f, 0.f, 0.f);
      if (l >= 0 && l < L_)
        v = *reinterpret_cast<const float4*>(xb + (size_t)l * D_ + kc + (kk << 2));
      const int tok = TOK + hh;
      xt[(kk << 2) + 0][tok] = v.x; xt[(kk << 2) + 1][tok] = v.y;
      xt[(kk << 2) + 2][tok] = v.z; xt[(kk << 2) + 3][tok] = v.w;
    }
    __syncthreads();

    // ---- conv for this chunk's 16 output channels ----
    {
      const int o = (c << 4) + oo_c;
      const float* wcp = Wc + o * 12;
      const float bco = bc[o];
      float acc0 = bco, acc1 = bco, acc2 = bco, acc3 = bco;
      const int tm1 = (tok0c == 0) ? TOK : tok0c - 1;
      const int tp4 = (tok0c == TOK - 4) ? TOK + 1 : tok0c + 4;
#pragma unroll
      for (int i = 0; i < 4; ++i) {
        const float w0 = wcp[i * 3 + 0], w1 = wcp[i * 3 + 1], w2 = wcp[i * 3 + 2];
        const float* row = &xt[cb_c + i][0];
        const float v0 = row[tm1], v1 = row[tok0c], v2 = row[tok0c + 1],
                    v3 = row[tok0c + 2], v4 = row[tok0c + 3], v5 = row[tp4];
        acc0 = fmaf(v2, w2, fmaf(v1, w1, fmaf(v0, w0, acc0)));
        acc1 = fmaf(v3, w2, fmaf(v2, w1, fmaf(v1, w0, acc1)));
        acc2 = fmaf(v4, w2, fmaf(v3, w1, fmaf(v2, w0, acc2)));
        acc3 = fmaf(v5, w2, fmaf(v4, w1, fmaf(v3, w0, acc3)));
      }
      *reinterpret_cast<float4*>(&pf[oo_c][tok0c]) =
          make_float4(acc0, acc1, acc2, acc3);
    }

    // ---- GEMM x-part: both matrices ----
    {
      const float* w1p = W1  + (size_t)kc * 128 + j0;
      const float* wbp = Wb1 + (size_t)kc * 128 + j0;
#pragma unroll 2
      for (int k = 0; k < KC; ++k) {
        const float4 w1 = *reinterpret_cast<const float4*>(w1p + (size_t)k * 128);
        const float4 wb = *reinterpret_cast<const float4*>(wbp + (size_t)k * 128);
        const float4 xa = *reinterpret_cast<const float4*>(&xt[k][tok0]);
        const float4 xbv = *reinterpret_cast<const float4*>(&xt[k][tok0 + 4]);
        const float xv[8] = {xa.x, xa.y, xa.z, xa.w, xbv.x, xbv.y, xbv.z, xbv.w};
#pragma unroll
        for (int i = 0; i < 8; ++i) {
          a1[i][0] = fmaf(xv[i], w1.x, a1[i][0]);
          a1[i][1] = fmaf(xv[i], w1.y, a1[i][1]);
          a1[i][2] = fmaf(xv[i], w1.z, a1[i][2]);
          a1[i][3] = fmaf(xv[i], w1.w, a1[i][3]);
          a2[i][0] = fmaf(xv[i], wb.x, a2[i][0]);
          a2[i][1] = fmaf(xv[i], wb.y, a2[i][1]);
          a2[i][2] = fmaf(xv[i], wb.z, a2[i][2]);
          a2[i][3] = fmaf(xv[i], wb.w, a2[i][3]);
        }
      }
    }
    __syncthreads();                   // pf writes visible

    // ---- GEMM pf-part ----
    {
      const float* wpp = Wb1 + (size_t)(512 + (c << 4)) * 128 + j0;
#pragma unroll 2
      for (int oo = 0; oo < 16; ++oo) {
        const float4 wp = *reinterpret_cast<const float4*>(wpp + (size_t)oo * 128);
        const float4 pa = *reinterpret_cast<const float4*>(&pf[oo][tok0]);
        const float4 pb = *reinterpret_cast<const float4*>(&pf[oo][tok0 + 4]);
        const float pv[8] = {pa.x, pa.y, pa.z, pa.w, pb.x, pb.y, pb.z, pb.w};
#pragma unroll
        for (int i = 0; i < 8; ++i) {
          a2[i][0] = fmaf(pv[i], wp.x, a2[i][0]);
          a2[i][1] = fmaf(pv[i], wp.y, a2[i][1]);
          a2[i][2] = fmaf(pv[i], wp.z, a2[i][2]);
          a2[i][3] = fmaf(pv[i], wp.w, a2[i][3]);
        }
      }
    }
  }

  // ---- epilogue: relu, project, cross-jq reduce, sigmoid ----
  float b1v[4], w2v[4], bbv[4], wv2[4];
#pragma unroll
  for (int jj = 0; jj < 4; ++jj) {
    b1v[jj] = b1[j0 + jj];  w2v[jj] = W2[j0 + jj];
    bbv[jj] = bb1[j0 + jj]; wv2[jj] = Wb2[j0 + jj];
  }
  const float bias2 = b2[0], biasb2 = bb2[0];
#pragma unroll
  for (int i = 0; i < 8; ++i) {
    float p1 = 0.f, p2 = 0.f;
#pragma unroll
    for (int jj = 0; jj < 4; ++jj) {
      const float h1 = a1[i][jj] + b1v[jj];
      if (h1 > 0.f) p1 = fmaf(h1, w2v[jj], p1);
      const float h2 = a2[i][jj] + bbv[jj];
      if (h2 > 0.f) p2 = fmaf(h2, wv2[jj], p2);
    }
#pragma unroll
    for (int off = 1; off < 32; off <<= 1) {
      p1 += __shfl_xor(p1, off, 64);
      p2 += __shfl_xor(p2, off, 64);
    }
    if (jq == 0) {
      const int gi = b * L_ + l0 + tok0 + i;
      const float content = 1.f / (1.f + expf(-(p1 + bias2)));
      const float bscore  = 1.f / (1.f + expf(-(p2 + biasb2)));
      signal[gi] = content * (1.f - bscore) * mask[gi];
    }
  }
}

// ---------------------------------------------------------------------------
// Exact 0.7-quantile per row via MSB-first radix select; keys cached in regs,
// 1024 threads, wave-0 shfl prefix-scan for bin selection.
// ---------------------------------------------------------------------------
__global__ __launch_bounds__(1024) void k_quantile(const float* __restrict__ signal,
                                                   float* __restrict__ thr)
{
  __shared__ unsigned int bins[256];
  __shared__ unsigned int sel_prefix;
  __shared__ int sel_rank;
  __shared__ unsigned int keys_out[2];
  const int b = blockIdx.x, t = threadIdx.x;
  const float* s = signal + b * L_;
  const int rank0 = 5733;   // floor(0.7f*8191f)

  unsigned int key[8];
#pragma unroll
  for (int i = 0; i < 8; ++i) {
    const unsigned int u = __float_as_uint(s[(i << 10) + t]);
    key[i] = (u & 0x80000000u) ? ~u : (u | 0x80000000u);
  }

  for (int which = 0; which < 2; ++which) {
    if (t == 0) { sel_prefix = 0u; sel_rank = rank0 + which; }
    __syncthreads();
    for (int round = 0; round < 4; ++round) {
      if (t < 256) bins[t] = 0u;
      __syncthreads();
      const unsigned int pre = sel_prefix;
      const int shift = 24 - 8 * round;
#pragma unroll
      for (int i = 0; i < 8; ++i) {
        if (round == 0 || (key[i] >> (shift + 8)) == pre)
          atomicAdd(&bins[(key[i] >> shift) & 255u], 1u);
      }
      __syncthreads();
      if (t < 64) {
        const unsigned int c0 = bins[(t << 2) + 0], c1 = bins[(t << 2) + 1];
        const unsigned int c2 = bins[(t << 2) + 2], c3 = bins[(t << 2) + 3];
        const unsigned int lsum = c0 + c1 + c2 + c3;
        unsigned int run = lsum;
#pragma unroll
        for (int off = 1; off < 64; off <<= 1) {
          const unsigned int v = __shfl_up(run, off, 64);
          if (t >= off) run += v;
        }
        const int r = sel_rank;
        if (r >= (int)(run - lsum) && r < (int)run) {
          int rr = r - (int)(run - lsum);
          unsigned int cbin;
          if (rr < (int)c0) { cbin = 0; }
          else if (rr < (int)(c0 + c1)) { cbin = 1; rr -= (int)c0; }
          else if (rr < (int)(c0 + c1 + c2)) { cbin = 2; rr -= (int)(c0 + c1); }
          else { cbin = 3; rr -= (int)(c0 + c1 + c2); }
          sel_rank = rr;
          sel_prefix = (pre << 8) | ((unsigned int)(t << 2) | cbin);
        }
      }
      __syncthreads();
    }
    if (t == 0) keys_out[which] = sel_prefix;
    __syncthreads();
  }
  if (t == 0) {
    const unsigned int k0 = keys_out[0], k1 = keys_out[1];
    const unsigned int u0 = (k0 & 0x80000000u) ? (k0 & 0x7fffffffu) : ~k0;
    const unsigned int u1 = (k1 & 0x80000000u) ? (k1 & 0x7fffffffu) : ~k1;
    const float v0 = __uint_as_float(u0);
    const float v1 = __uint_as_float(u1);
    const float g = 0.7f * 8191.0f - 5733.0f;   // float32, mimics jnp
    thr[b] = v0 + g * (v1 - v0);
  }
}

// ---------------------------------------------------------------------------
// Greedy enforce: wave-parallel chain walk over candidate bits in registers.
// ---------------------------------------------------------------------------
__global__ __launch_bounds__(256) void k_enforce(
    const float* __restrict__ signal, const float* __restrict__ thr_arr,
    int* __restrict__ starts, int* __restrict__ nlast, float* __restrict__ bounds)
{
  __shared__ unsigned long long cw[L_ / 64];   // 128 words
  __shared__ unsigned char nb[L_];
  __shared__ int tsum[256];
  __shared__ int offs[257];
  const int b = blockIdx.x, t = threadIdx.x;
  const float thr = thr_arr[b];
  const float* s = signal + b * L_;
  const int wave = t >> 6, lane = t & 63;

  for (int i = 0; i < L_ / 256; ++i) {
    const unsigned long long m = __ballot(s[i * 256 + t] < thr);
    if (lane == 0) cw[i * 4 + wave] = m;
  }
  {
    const int base = t * (L_ / 256);
    for (int i = 0; i < L_ / 256; ++i) nb[base + i] = 0;
  }
  __syncthreads();
  if (t == 0) cw[L_ / 64 - 1] |= (1ull << 63);
  __syncthreads();

  if (t < 64) {
    const unsigned long long w0 = cw[lane];
    const unsigned long long w1 = cw[64 + lane];
    int st = 0;
    for (;;) {
      const int from = st + 4;
      if (from >= L_) break;
      const int r0 = from - (lane << 6);
      unsigned long long m0 = (r0 <= 0) ? w0 : (r0 >= 64 ? 0ull : (w0 & (~0ull << r0)));
      const int r1 = from - ((64 + lane) << 6);
      unsigned long long m1 = (r1 <= 0) ? w1 : (r1 >= 64 ? 0ull : (w1 & (~0ull << r1)));
      const unsigned long long b0 = __ballot(m0 != 0ull);
      int p;
      if (b0 != 0ull) {
        const int wsel = __ffsll(b0) - 1;
        const unsigned long long mw = __shfl(m0, wsel, 64);
        p = (wsel << 6) + __ffsll(mw) - 1;
      } else {
        const unsigned long long b1m = __ballot(m1 != 0ull);
        if (b1m == 0ull) break;
        const int wsel = __ffsll(b1m) - 1;
        const unsigned long long mw = __shfl(m1, wsel, 64);
        p = ((64 + wsel) << 6) + __ffsll(mw) - 1;
      }
      const int ps = p - st;
      if (lane == 0) nb[p] = 1;
      const int k = (ps + 15) >> 4;
      if (k > 1) {
        int sz = ps / k; if (sz < 1) sz = 1;
        for (int j = 1 + lane; j < k; j += 64) nb[st + j * sz] = 1;
      }
      st = p;
    }
  }
  __syncthreads();

  const int base = t * 32;
  int ls = 0;
  for (int i = 0; i < 32; ++i) ls += nb[base + i];
  tsum[t] = ls;
  __syncthreads();
  if (t == 0) {
    int r = 0;
    for (int i = 0; i < 256; ++i) { offs[i] = r; r += tsum[i]; }
    offs[256] = r;
  }
  __syncthreads();

  int run = offs[t];
  for (int i = 0; i < 32; ++i) {
    run += nb[base + i];
    if (nb[base + i]) starts[b * L_ + run] = base + i;
  }
  if (t == 0) { starts[b * L_ + 0] = 0; nlast[b] = offs[256]; }
  const int total = offs[256];
  for (int i = t; i < L_; i += 256) {
    bounds[b * L_ + i] = (i >= 1 && i <= total) ? 1.0f : 0.0f;
  }
}

// ---------------------------------------------------------------------------
// e[tok] = sum_d (x*mask)^2
// ---------------------------------------------------------------------------
__global__ __launch_bounds__(256) void k_e(const float* __restrict__ x,
                                           const float* __restrict__ mask,
                                           float* __restrict__ e)
{
  const int wave = threadIdx.x >> 6, lane = threadIdx.x & 63;
  const int tok = (blockIdx.x << 2) + wave;
  const float m = mask[tok];
  const float* xr = x + (size_t)tok * D_ + (lane << 3);
  const float4 v0 = reinterpret_cast<const float4*>(xr)[0];
  const float4 v1 = reinterpret_cast<const float4*>(xr)[1];
  float acc = 0.f, q;
  q = v0.x * m; acc = fmaf(q, q, acc);
  q = v0.y * m; acc = fmaf(q, q, acc);
  q = v0.z * m; acc = fmaf(q, q, acc);
  q = v0.w * m; acc = fmaf(q, q, acc);
  q = v1.x * m; acc = fmaf(q, q, acc);
  q = v1.y * m; acc = fmaf(q, q, acc);
  q = v1.z * m; acc = fmaf(q, q, acc);
  q = v1.w * m; acc = fmaf(q, q, acc);
#pragma unroll
  for (int off = 32; off > 0; off >>= 1) acc += __shfl_down(acc, off, 64);
  if (lane == 0) e[tok] = acc;
}

// ---------------------------------------------------------------------------
// Segment softmax-merge: one wave per segment id; dead sids write zeros.
// ---------------------------------------------------------------------------
__global__ __launch_bounds__(64) void k_merge(const float* __restrict__ x,
    const float* __restrict__ mask, const float* __restrict__ e,
    const int* __restrict__ starts, const int* __restrict__ nlast,
    float* __restrict__ merged)
{
  const int idx = blockIdx.x;
  const int b   = idx >> 13;            // L_ == 8192
  const int sid = idx & (L_ - 1);
  const int n = nlast[b];
  const int lane = threadIdx.x;
  const int c0 = lane << 3;
  float* o = merged + (size_t)(b * L_ + sid) * D_ + c0;
  if (sid > n) {
    const float4 z = make_float4(0.f, 0.f, 0.f, 0.f);
    reinterpret_cast<float4*>(o)[0] = z;
    reinterpret_cast<float4*>(o)[1] = z;
    return;
  }
  const int t0 = starts[b * L_ + sid];
  const int t1 = (sid < n) ? starts[b * L_ + sid + 1] : L_;
  const float* eb = e + b * L_;

  float mx = -INFINITY;
  for (int p = t0; p < t1; ++p) mx = fmaxf(mx, eb[p]);
  float den = 0.f;
  for (int p = t0; p < t1; ++p) den += expf(eb[p] - mx);

  float acc[8] = {0,0,0,0,0,0,0,0};
  for (int p = t0; p < t1; ++p) {
    const float wn = expf(eb[p] - mx) / den;
    const float sc = wn * mask[b * L_ + p];
    const float* xr = x + ((size_t)(b * L_ + p)) * D_ + c0;
    const float4 u0 = reinterpret_cast<const float4*>(xr)[0];
    const float4 u1 = reinterpret_cast<const float4*>(xr)[1];
    acc[0] = fmaf(sc, u0.x, acc[0]); acc[1] = fmaf(sc, u0.y, acc[1]);
    acc[2] = fmaf(sc, u0.z, acc[2]); acc[3] = fmaf(sc, u0.w, acc[3]);
    acc[4] = fmaf(sc, u1.x, acc[4]); acc[5] = fmaf(sc, u1.y, acc[5]);
    acc[6] = fmaf(sc, u1.z, acc[6]); acc[7] = fmaf(sc, u1.w, acc[7]);
  }
  reinterpret_cast<float4*>(o)[0] = make_float4(acc[0], acc[1], acc[2], acc[3]);
  reinterpret_cast<float4*>(o)[1] = make_float4(acc[4], acc[5], acc[6], acc[7]);
}

// ---------------------------------------------------------------------------
extern "C" void kernel_launch(void* const* d_in, const int* in_sizes, int n_in,
                              void* d_out, int out_size, void* d_ws, size_t ws_size,
                              hipStream_t stream) {
  (void)in_sizes; (void)n_in; (void)out_size; (void)ws_size;
  const float* x    = (const float*)d_in[0];
  const float* mask = (const float*)d_in[1];
  const float* W1   = (const float*)d_in[2];
  const float* b1   = (const float*)d_in[3];
  const float* W2   = (const float*)d_in[4];
  const float* b2   = (const float*)d_in[5];
  const float* Wc   = (const float*)d_in[6];
  const float* bc   = (const float*)d_in[7];
  const float* Wb1  = (const float*)d_in[8];
  const float* bb1  = (const float*)d_in[9];
  const float* Wb2  = (const float*)d_in[10];
  const float* bb2  = (const float*)d_in[11];

  float* merged = (float*)d_out;
  float* bounds = (float*)d_out + (size_t)BL_ * D_;

  char* ws = (char*)d_ws;
  float* signal = (float*)(ws);                          // 128 KB
  float* e      = (float*)(ws + (size_t)BL_ * 4);        // 128 KB
  int*   starts = (int*)  (ws + (size_t)BL_ * 8);        // 128 KB
  int*   nlast  = (int*)  (ws + (size_t)BL_ * 12);       // 64 B
  float* thr    = (float*)(ws + (size_t)BL_ * 12 + 64);  // 64 B

  k_signal<<<BL_ / TOK, 256, 0, stream>>>(x, mask, W1, b1, W2, b2, Wc, bc,
                                          Wb1, bb1, Wb2, bb2, signal);
  k_quantile<<<B_, 1024, 0, stream>>>(signal, thr);
  k_enforce<<<B_, 256, 0, stream>>>(signal, thr, starts, nlast, bounds);
  k_e<<<BL_ / 4, 256, 0, stream>>>(x, mask, e);
  k_merge<<<BL_, 64, 0, stream>>>(x, mask, e, starts, nlast, merged);
}

// Round 4
// 372.258 us; speedup vs baseline: 3.2405x; 2.1047x over previous
//
#include <hip/hip_runtime.h>
#include <math.h>

#define B_  4
#define L_  8192
#define D_  512
#define BL_ (B_*L_)
#define TOK 64
#define KC  32
#define NCH (D_/KC)

// ---------------------------------------------------------------------------
// Signal: content = sigmoid(relu(x@W1+b1)@W2+b2)
//         pf      = groupedconv(x)+bc  (computed per K-chunk into LDS)
//         bscore  = sigmoid(relu([x,pf]@Wb1+bb1)@Wb2+bb2)
//         signal  = content*(1-bscore)*mask
// 64 tokens/block, K-chunked. Thread = (jq 0..31, tw 0..7) owns 8 tok x 4 j.
// ---------------------------------------------------------------------------
__global__ __launch_bounds__(256, 2) void k_signal(
    const float* __restrict__ x, const float* __restrict__ mask,
    const float* __restrict__ W1, const float* __restrict__ b1,
    const float* __restrict__ W2, const float* __restrict__ b2,
    const float* __restrict__ Wc, const float* __restrict__ bc,
    const float* __restrict__ Wb1, const float* __restrict__ bb1,
    const float* __restrict__ Wb2, const float* __restrict__ bb2,
    float* __restrict__ signal)
{
  __shared__ float xt[KC][TOK + 4];
  __shared__ float pf[16][TOK];

  const int t   = threadIdx.x;
  const int blk = blockIdx.x;
  const int b   = blk >> 7;
  const int l0  = (blk & 127) * TOK;
  const float* xb = x + (size_t)b * L_ * D_;

  const int jq = t & 31, tw = t >> 5;
  const int j0 = jq << 2, tok0 = tw << 3;

  float a1[8][4], a2[8][4];
#pragma unroll
  for (int i = 0; i < 8; ++i)
#pragma unroll
    for (int j = 0; j < 4; ++j) { a1[i][j] = 0.f; a2[i][j] = 0.f; }

  const int oo_c   = t >> 4;
  const int tokq_c = t & 15;
  const int cb_c   = (oo_c >> 1) << 2;
  const int tok0c  = tokq_c << 2;

  for (int c = 0; c < NCH; ++c) {
    const int kc = c << 5;
    __syncthreads();

#pragma unroll
    for (int rep = 0; rep < 2; ++rep) {
      const int slot = (rep << 8) + t;
      const int tok = slot >> 3, kk = slot & 7;
      const float4 v = *reinterpret_cast<const float4*>(
          xb + (size_t)(l0 + tok) * D_ + kc + (kk << 2));
      xt[(kk << 2) + 0][tok] = v.x; xt[(kk << 2) + 1][tok] = v.y;
      xt[(kk << 2) + 2][tok] = v.z; xt[(kk << 2) + 3][tok] = v.w;
    }
    if (t < 16) {
      const int hh = t >> 3, kk = t & 7;
      const int l = hh ? (l0 + TOK) : (l0 - 1);
      float4 v = make_float4(0.f, 0.f, 0.f, 0.f);
      if (l >= 0 && l < L_)
        v = *reinterpret_cast<const float4*>(xb + (size_t)l * D_ + kc + (kk << 2));
      const int tok = TOK + hh;
      xt[(kk << 2) + 0][tok] = v.x; xt[(kk << 2) + 1][tok] = v.y;
      xt[(kk << 2) + 2][tok] = v.z; xt[(kk << 2) + 3][tok] = v.w;
    }
    __syncthreads();

    {
      const int o = (c << 4) + oo_c;
      const float* wcp = Wc + o * 12;
      const float bco = bc[o];
      float acc0 = bco, acc1 = bco, acc2 = bco, acc3 = bco;
      const int tm1 = (tok0c == 0) ? TOK : tok0c - 1;
      const int tp4 = (tok0c == TOK - 4) ? TOK + 1 : tok0c + 4;
#pragma unroll
      for (int i = 0; i < 4; ++i) {
        const float w0 = wcp[i * 3 + 0], w1 = wcp[i * 3 + 1], w2 = wcp[i * 3 + 2];
        const float* row = &xt[cb_c + i][0];
        const float v0 = row[tm1], v1 = row[tok0c], v2 = row[tok0c + 1],
                    v3 = row[tok0c + 2], v4 = row[tok0c + 3], v5 = row[tp4];
        acc0 = fmaf(v2, w2, fmaf(v1, w1, fmaf(v0, w0, acc0)));
        acc1 = fmaf(v3, w2, fmaf(v2, w1, fmaf(v1, w0, acc1)));
        acc2 = fmaf(v4, w2, fmaf(v3, w1, fmaf(v2, w0, acc2)));
        acc3 = fmaf(v5, w2, fmaf(v4, w1, fmaf(v3, w0, acc3)));
      }
      *reinterpret_cast<float4*>(&pf[oo_c][tok0c]) =
          make_float4(acc0, acc1, acc2, acc3);
    }

    {
      const float* w1p = W1  + (size_t)kc * 128 + j0;
      const float* wbp = Wb1 + (size_t)kc * 128 + j0;
#pragma unroll 2
      for (int k = 0; k < KC; ++k) {
        const float4 w1 = *reinterpret_cast<const float4*>(w1p + (size_t)k * 128);
        const float4 wb = *reinterpret_cast<const float4*>(wbp + (size_t)k * 128);
        const float4 xa = *reinterpret_cast<const float4*>(&xt[k][tok0]);
        const float4 xbv = *reinterpret_cast<const float4*>(&xt[k][tok0 + 4]);
        const float xv[8] = {xa.x, xa.y, xa.z, xa.w, xbv.x, xbv.y, xbv.z, xbv.w};
#pragma unroll
        for (int i = 0; i < 8; ++i) {
          a1[i][0] = fmaf(xv[i], w1.x, a1[i][0]);
          a1[i][1] = fmaf(xv[i], w1.y, a1[i][1]);
          a1[i][2] = fmaf(xv[i], w1.z, a1[i][2]);
          a1[i][3] = fmaf(xv[i], w1.w, a1[i][3]);
          a2[i][0] = fmaf(xv[i], wb.x, a2[i][0]);
          a2[i][1] = fmaf(xv[i], wb.y, a2[i][1]);
          a2[i][2] = fmaf(xv[i], wb.z, a2[i][2]);
          a2[i][3] = fmaf(xv[i], wb.w, a2[i][3]);
        }
      }
    }
    __syncthreads();

    {
      const float* wpp = Wb1 + (size_t)(512 + (c << 4)) * 128 + j0;
#pragma unroll 2
      for (int oo = 0; oo < 16; ++oo) {
        const float4 wp = *reinterpret_cast<const float4*>(wpp + (size_t)oo * 128);
        const float4 pa = *reinterpret_cast<const float4*>(&pf[oo][tok0]);
        const float4 pb = *reinterpret_cast<const float4*>(&pf[oo][tok0 + 4]);
        const float pv[8] = {pa.x, pa.y, pa.z, pa.w, pb.x, pb.y, pb.z, pb.w};
#pragma unroll
        for (int i = 0; i < 8; ++i) {
          a2[i][0] = fmaf(pv[i], wp.x, a2[i][0]);
          a2[i][1] = fmaf(pv[i], wp.y, a2[i][1]);
          a2[i][2] = fmaf(pv[i], wp.z, a2[i][2]);
          a2[i][3] = fmaf(pv[i], wp.w, a2[i][3]);
        }
      }
    }
  }

  float b1v[4], w2v[4], bbv[4], wv2[4];
#pragma unroll
  for (int jj = 0; jj < 4; ++jj) {
    b1v[jj] = b1[j0 + jj];  w2v[jj] = W2[j0 + jj];
    bbv[jj] = bb1[j0 + jj]; wv2[jj] = Wb2[j0 + jj];
  }
  const float bias2 = b2[0], biasb2 = bb2[0];
#pragma unroll
  for (int i = 0; i < 8; ++i) {
    float p1 = 0.f, p2 = 0.f;
#pragma unroll
    for (int jj = 0; jj < 4; ++jj) {
      const float h1 = a1[i][jj] + b1v[jj];
      if (h1 > 0.f) p1 = fmaf(h1, w2v[jj], p1);
      const float h2 = a2[i][jj] + bbv[jj];
      if (h2 > 0.f) p2 = fmaf(h2, wv2[jj], p2);
    }
#pragma unroll
    for (int off = 1; off < 32; off <<= 1) {
      p1 += __shfl_xor(p1, off, 64);
      p2 += __shfl_xor(p2, off, 64);
    }
    if (jq == 0) {
      const int gi = b * L_ + l0 + tok0 + i;
      const float content = 1.f / (1.f + expf(-(p1 + bias2)));
      const float bscore  = 1.f / (1.f + expf(-(p2 + biasb2)));
      signal[gi] = content * (1.f - bscore) * mask[gi];
    }
  }
}

// ---------------------------------------------------------------------------
// Exact 0.7-quantile per row via MSB-first radix select; keys in regs.
// ---------------------------------------------------------------------------
__global__ __launch_bounds__(1024) void k_quantile(const float* __restrict__ signal,
                                                   float* __restrict__ thr)
{
  __shared__ unsigned int bins[256];
  __shared__ unsigned int sel_prefix;
  __shared__ int sel_rank;
  __shared__ unsigned int keys_out[2];
  const int b = blockIdx.x, t = threadIdx.x;
  const float* s = signal + b * L_;
  const int rank0 = 5733;

  unsigned int key[8];
#pragma unroll
  for (int i = 0; i < 8; ++i) {
    const unsigned int u = __float_as_uint(s[(i << 10) + t]);
    key[i] = (u & 0x80000000u) ? ~u : (u | 0x80000000u);
  }

  for (int which = 0; which < 2; ++which) {
    if (t == 0) { sel_prefix = 0u; sel_rank = rank0 + which; }
    __syncthreads();
    for (int round = 0; round < 4; ++round) {
      if (t < 256) bins[t] = 0u;
      __syncthreads();
      const unsigned int pre = sel_prefix;
      const int shift = 24 - 8 * round;
#pragma unroll
      for (int i = 0; i < 8; ++i) {
        if (round == 0 || (key[i] >> (shift + 8)) == pre)
          atomicAdd(&bins[(key[i] >> shift) & 255u], 1u);
      }
      __syncthreads();
      if (t < 64) {
        const unsigned int c0 = bins[(t << 2) + 0], c1 = bins[(t << 2) + 1];
        const unsigned int c2 = bins[(t << 2) + 2], c3 = bins[(t << 2) + 3];
        const unsigned int lsum = c0 + c1 + c2 + c3;
        unsigned int run = lsum;
#pragma unroll
        for (int off = 1; off < 64; off <<= 1) {
          const unsigned int v = __shfl_up(run, off, 64);
          if (t >= off) run += v;
        }
        const int r = sel_rank;
        if (r >= (int)(run - lsum) && r < (int)run) {
          int rr = r - (int)(run - lsum);
          unsigned int cbin;
          if (rr < (int)c0) { cbin = 0; }
          else if (rr < (int)(c0 + c1)) { cbin = 1; rr -= (int)c0; }
          else if (rr < (int)(c0 + c1 + c2)) { cbin = 2; rr -= (int)(c0 + c1); }
          else { cbin = 3; rr -= (int)(c0 + c1 + c2); }
          sel_rank = rr;
          sel_prefix = (pre << 8) | ((unsigned int)(t << 2) | cbin);
        }
      }
      __syncthreads();
    }
    if (t == 0) keys_out[which] = sel_prefix;
    __syncthreads();
  }
  if (t == 0) {
    const unsigned int k0 = keys_out[0], k1 = keys_out[1];
    const unsigned int u0 = (k0 & 0x80000000u) ? (k0 & 0x7fffffffu) : ~k0;
    const unsigned int u1 = (k1 & 0x80000000u) ? (k1 & 0x7fffffffu) : ~k1;
    const float v0 = __uint_as_float(u0);
    const float v1 = __uint_as_float(u1);
    const float g = 0.7f * 8191.0f - 5733.0f;
    thr[b] = v0 + g * (v1 - v0);
  }
}

// ---------------------------------------------------------------------------
// Greedy enforce via block-decomposed chain:
//   invariant: entering a 64-pos block at bs, no candidate lies in [st+4,bs),
//   so in-block behavior depends only on off = clamp(st+4-bs, 0, 3).
//   (1) 512 (block,class) sims in parallel registers
//   (2) serial 128-step state scan over tiny LDS tables (one thread)
//   (3) parallel per-block emission of acceptance+split bytes
// ---------------------------------------------------------------------------
__device__ __forceinline__ int chain_sim(unsigned long long w, int from) {
  int last = -1;
  while (from < 64) {
    const unsigned long long m = w & (~0ull << from);
    if (m == 0ull) break;
    const int p = __ffsll(m) - 1;
    last = p;
    from = p + 4;
  }
  return last;
}

__global__ __launch_bounds__(256) void k_enforce(
    const float* __restrict__ signal, const float* __restrict__ thr_arr,
    int* __restrict__ starts, int* __restrict__ nlast, float* __restrict__ bounds)
{
  __shared__ unsigned long long cw[128];
  __shared__ unsigned char nb[L_];
  __shared__ signed char tbl[128][4];
  __shared__ int st_in[128];
  __shared__ int tsum[256];
  __shared__ int offs[257];
  const int b = blockIdx.x, t = threadIdx.x;
  const float thr = thr_arr[b];
  const float* s = signal + b * L_;
  const int wave = t >> 6, lane = t & 63;

  // candidate bitmap (batched loads + ballots) and nb zero-init
#pragma unroll
  for (int g = 0; g < 4; ++g) {
    float vv[8];
#pragma unroll
    for (int i = 0; i < 8; ++i) vv[i] = s[((g << 3) + i) * 256 + t];
#pragma unroll
    for (int i = 0; i < 8; ++i) {
      const unsigned long long m = __ballot(vv[i] < thr);
      if (lane == 0) cw[((g << 3) + i) * 4 + wave] = m;
    }
  }
  {
    const int base = t * 32;
    for (int i = 0; i < 32; ++i) nb[base + i] = 0;
  }
  __syncthreads();
  if (t == 0) cw[127] |= (1ull << 63);
  __syncthreads();

  // (1) per-block transition tables: 512 sims, classes 0..3
  for (int idx = t; idx < 512; idx += 256) {
    const int blk = idx >> 2, cls = idx & 3;
    tbl[blk][cls] = (signed char)chain_sim(cw[blk], cls);
  }
  __syncthreads();

  // (2) serial state scan
  if (t == 0) {
    int st = 0;
    for (int blk = 0; blk < 128; ++blk) {
      const int bs = blk << 6;
      st_in[blk] = st;
      int pl;
      if (blk == 0) {
        pl = chain_sim(cw[0], 4);
      } else {
        int off = st + 4 - bs;
        if (off < 0) off = 0;
        pl = tbl[blk][off];
      }
      if (pl >= 0) st = bs + pl;
    }
  }
  __syncthreads();

  // (3) parallel emission
  if (t < 128) {
    const int bs = t << 6;
    const unsigned long long w = cw[t];
    int st = st_in[t];
    int from = st + 4 - bs;
    if (from < 0) from = 0;
    while (from < 64) {
      const unsigned long long m = w & (~0ull << from);
      if (m == 0ull) break;
      const int p_rel = __ffsll(m) - 1;
      const int p = bs + p_rel;
      nb[p] = 1;
      const int ps = p - st;
      const int k = (ps + 15) >> 4;
      if (k > 1) {
        int sz = ps / k; if (sz < 1) sz = 1;
        for (int j = 1; j < k; ++j) nb[st + j * sz] = 1;
      }
      st = p;
      from = p_rel + 4;
    }
  }
  __syncthreads();

  // prefix scan -> starts / nlast / bounds (unchanged)
  const int base = t * 32;
  int ls = 0;
  for (int i = 0; i < 32; ++i) ls += nb[base + i];
  tsum[t] = ls;
  __syncthreads();
  if (t == 0) {
    int r = 0;
    for (int i = 0; i < 256; ++i) { offs[i] = r; r += tsum[i]; }
    offs[256] = r;
  }
  __syncthreads();

  int run = offs[t];
  for (int i = 0; i < 32; ++i) {
    run += nb[base + i];
    if (nb[base + i]) starts[b * L_ + run] = base + i;
  }
  if (t == 0) { starts[b * L_ + 0] = 0; nlast[b] = offs[256]; }
  const int total = offs[256];
  for (int i = t; i < L_; i += 256) {
    bounds[b * L_ + i] = (i >= 1 && i <= total) ? 1.0f : 0.0f;
  }
}

// ---------------------------------------------------------------------------
// e[tok] = sum_d (x*mask)^2
// ---------------------------------------------------------------------------
__global__ __launch_bounds__(256) void k_e(const float* __restrict__ x,
                                           const float* __restrict__ mask,
                                           float* __restrict__ e)
{
  const int wave = threadIdx.x >> 6, lane = threadIdx.x & 63;
  const int tok = (blockIdx.x << 2) + wave;
  const float m = mask[tok];
  const float* xr = x + (size_t)tok * D_ + (lane << 3);
  const float4 v0 = reinterpret_cast<const float4*>(xr)[0];
  const float4 v1 = reinterpret_cast<const float4*>(xr)[1];
  float acc = 0.f, q;
  q = v0.x * m; acc = fmaf(q, q, acc);
  q = v0.y * m; acc = fmaf(q, q, acc);
  q = v0.z * m; acc = fmaf(q, q, acc);
  q = v0.w * m; acc = fmaf(q, q, acc);
  q = v1.x * m; acc = fmaf(q, q, acc);
  q = v1.y * m; acc = fmaf(q, q, acc);
  q = v1.z * m; acc = fmaf(q, q, acc);
  q = v1.w * m; acc = fmaf(q, q, acc);
#pragma unroll
  for (int off = 32; off > 0; off >>= 1) acc += __shfl_down(acc, off, 64);
  if (lane == 0) e[tok] = acc;
}

// ---------------------------------------------------------------------------
// Segment softmax-merge: one wave per segment id; dead sids write zeros.
// ---------------------------------------------------------------------------
__global__ __launch_bounds__(64) void k_merge(const float* __restrict__ x,
    const float* __restrict__ mask, const float* __restrict__ e,
    const int* __restrict__ starts, const int* __restrict__ nlast,
    float* __restrict__ merged)
{
  const int idx = blockIdx.x;
  const int b   = idx >> 13;
  const int sid = idx & (L_ - 1);
  const int n = nlast[b];
  const int lane = threadIdx.x;
  const int c0 = lane << 3;
  float* o = merged + (size_t)(b * L_ + sid) * D_ + c0;
  if (sid > n) {
    const float4 z = make_float4(0.f, 0.f, 0.f, 0.f);
    reinterpret_cast<float4*>(o)[0] = z;
    reinterpret_cast<float4*>(o)[1] = z;
    return;
  }
  const int t0 = starts[b * L_ + sid];
  const int t1 = (sid < n) ? starts[b * L_ + sid + 1] : L_;
  const float* eb = e + b * L_;

  float mx = -INFINITY;
  for (int p = t0; p < t1; ++p) mx = fmaxf(mx, eb[p]);
  float den = 0.f;
  for (int p = t0; p < t1; ++p) den += expf(eb[p] - mx);

  float acc[8] = {0,0,0,0,0,0,0,0};
  for (int p = t0; p < t1; ++p) {
    const float wn = expf(eb[p] - mx) / den;
    const float sc = wn * mask[b * L_ + p];
    const float* xr = x + ((size_t)(b * L_ + p)) * D_ + c0;
    const float4 u0 = reinterpret_cast<const float4*>(xr)[0];
    const float4 u1 = reinterpret_cast<const float4*>(xr)[1];
    acc[0] = fmaf(sc, u0.x, acc[0]); acc[1] = fmaf(sc, u0.y, acc[1]);
    acc[2] = fmaf(sc, u0.z, acc[2]); acc[3] = fmaf(sc, u0.w, acc[3]);
    acc[4] = fmaf(sc, u1.x, acc[4]); acc[5] = fmaf(sc, u1.y, acc[5]);
    acc[6] = fmaf(sc, u1.z, acc[6]); acc[7] = fmaf(sc, u1.w, acc[7]);
  }
  reinterpret_cast<float4*>(o)[0] = make_float4(acc[0], acc[1], acc[2], acc[3]);
  reinterpret_cast<float4*>(o)[1] = make_float4(acc[4], acc[5], acc[6], acc[7]);
}

// ---------------------------------------------------------------------------
extern "C" void kernel_launch(void* const* d_in, const int* in_sizes, int n_in,
                              void* d_out, int out_size, void* d_ws, size_t ws_size,
                              hipStream_t stream) {
  (void)in_sizes; (void)n_in; (void)out_size; (void)ws_size;
  const float* x    = (const float*)d_in[0];
  const float* mask = (const float*)d_in[1];
  const float* W1   = (const float*)d_in[2];
  const float* b1   = (const float*)d_in[3];
  const float* W2   = (const float*)d_in[4];
  const float* b2   = (const float*)d_in[5];
  const float* Wc   = (const float*)d_in[6];
  const float* bc   = (const float*)d_in[7];
  const float* Wb1  = (const float*)d_in[8];
  const float* bb1  = (const float*)d_in[9];
  const float* Wb2  = (const float*)d_in[10];
  const float* bb2  = (const float*)d_in[11];

  float* merged = (float*)d_out;
  float* bounds = (float*)d_out + (size_t)BL_ * D_;

  char* ws = (char*)d_ws;
  float* signal = (float*)(ws);
  float* e      = (float*)(ws + (size_t)BL_ * 4);
  int*   starts = (int*)  (ws + (size_t)BL_ * 8);
  int*   nlast  = (int*)  (ws + (size_t)BL_ * 12);
  float* thr    = (float*)(ws + (size_t)BL_ * 12 + 64);

  k_signal<<<BL_ / TOK, 256, 0, stream>>>(x, mask, W1, b1, W2, b2, Wc, bc,
                                          Wb1, bb1, Wb2, bb2, signal);
  k_quantile<<<B_, 1024, 0, stream>>>(signal, thr);
  k_enforce<<<B_, 256, 0, stream>>>(signal, thr, starts, nlast, bounds);
  k_e<<<BL_ / 4, 256, 0, stream>>>(x, mask, e);
  k_merge<<<BL_, 64, 0, stream>>>(x, mask, e, starts, nlast, merged);
}

// Round 5
// 341.022 us; speedup vs baseline: 3.5373x; 1.0916x over previous
//
#include <hip/hip_runtime.h>
#include <math.h>

#define B_  4
#define L_  8192
#define D_  512
#define BL_ (B_*L_)
#define TOK 32
#define XS  36            // row stride: 16B-aligned, ==4 mod 32 (2-way banks only)
#define KC  32
#define NCH (D_/KC)

// ---------------------------------------------------------------------------
// Signal + e:
//   content = sigmoid(relu(x@W1+b1)@W2+b2)
//   pf      = groupedconv(x)+bc  (per K-chunk into LDS)
//   bscore  = sigmoid(relu([x,pf]@Wb1+bb1)@Wb2+bb2)
//   signal  = content*(1-bscore)*mask;  e = mask^2 * sum(x^2)
// 32 tokens/block, 1024 blocks (4/CU). Thread = (jq,tw) -> 4 tok x 4 j.
// ---------------------------------------------------------------------------
__global__ __launch_bounds__(256, 4) void k_signal(
    const float* __restrict__ x, const float* __restrict__ mask,
    const float* __restrict__ W1, const float* __restrict__ b1,
    const float* __restrict__ W2, const float* __restrict__ b2,
    const float* __restrict__ Wc, const float* __restrict__ bc,
    const float* __restrict__ Wb1, const float* __restrict__ bb1,
    const float* __restrict__ Wb2, const float* __restrict__ bb2,
    float* __restrict__ signal, float* __restrict__ e)
{
  __shared__ float xt[KC][XS];   // [k][tok]; col 32 = l0-1, col 33 = l0+32
  __shared__ float pf[16][XS];   // conv out chunk [oo][tok]

  const int t   = threadIdx.x;
  const int blk = blockIdx.x;          // 1024 = 4 b x 256 tiles
  const int b   = blk >> 8;
  const int l0  = (blk & 255) * TOK;
  const float* xb = x + (size_t)b * L_ * D_;

  const int jq = t & 31, tw = t >> 5;
  const int j0 = jq << 2, tok0 = tw << 2;

  // staging / e role
  const int stok = t >> 3, skk = t & 7;
  // conv role
  const int oo_c  = t >> 4;            // 0..15
  const int tokq  = t & 15;
  const int cb_c  = (oo_c >> 1) << 2;  // relative channel base
  const int tok0c = tokq << 1;         // 2 tokens per thread

  float a1[4][4], a2[4][4];
#pragma unroll
  for (int i = 0; i < 4; ++i)
#pragma unroll
    for (int j = 0; j < 4; ++j) { a1[i][j] = 0.f; a2[i][j] = 0.f; }
  float esacc = 0.f;

  for (int c = 0; c < NCH; ++c) {
    const int kc = c << 5;
    __syncthreads();                   // xt/pf free of previous readers

    // ---- stage x chunk transposed; accumulate sum(x^2) ----
    {
      const float4 v = *reinterpret_cast<const float4*>(
          xb + (size_t)(l0 + stok) * D_ + kc + (skk << 2));
      esacc = fmaf(v.x, v.x, esacc); esacc = fmaf(v.y, v.y, esacc);
      esacc = fmaf(v.z, v.z, esacc); esacc = fmaf(v.w, v.w, esacc);
      const int r = skk << 2;
      xt[r + 0][stok] = v.x; xt[r + 1][stok] = v.y;
      xt[r + 2][stok] = v.z; xt[r + 3][stok] = v.w;
    }
    if (t < 16) {
      const int hh = t >> 3, kk = t & 7;
      const int l = hh ? (l0 + TOK) : (l0 - 1);
      float4 v = make_float4(0.f, 0.f, 0.f, 0.f);
      if (l >= 0 && l < L_)
        v = *reinterpret_cast<const float4*>(xb + (size_t)l * D_ + kc + (kk << 2));
      const int r = kk << 2, col = TOK + hh;
      xt[r + 0][col] = v.x; xt[r + 1][col] = v.y;
      xt[r + 2][col] = v.z; xt[r + 3][col] = v.w;
    }
    __syncthreads();

    // ---- conv: this chunk's 16 output channels, 2 tokens/thread ----
    {
      const int o = (c << 4) + oo_c;
      const float* wcp = Wc + o * 12;
      const float bco = bc[o];
      float acc0 = bco, acc1 = bco;
      const int tm1 = (tok0c == 0) ? TOK : tok0c - 1;
      const int tp2 = (tok0c == TOK - 2) ? TOK + 1 : tok0c + 2;
#pragma unroll
      for (int i = 0; i < 4; ++i) {
        const float w0 = wcp[i * 3 + 0], w1 = wcp[i * 3 + 1], w2 = wcp[i * 3 + 2];
        const float* row = &xt[cb_c + i][0];
        const float v0 = row[tm1], v1 = row[tok0c], v2 = row[tok0c + 1],
                    v3 = row[tp2];
        acc0 = fmaf(v2, w2, fmaf(v1, w1, fmaf(v0, w0, acc0)));
        acc1 = fmaf(v3, w2, fmaf(v2, w1, fmaf(v1, w0, acc1)));
      }
      pf[oo_c][tok0c]     = acc0;
      pf[oo_c][tok0c + 1] = acc1;
    }

    // ---- GEMM x-part: both matrices ----
    {
      const float* w1p = W1  + (size_t)kc * 128 + j0;
      const float* wbp = Wb1 + (size_t)kc * 128 + j0;
#pragma unroll 2
      for (int k = 0; k < KC; ++k) {
        const float4 w1 = *reinterpret_cast<const float4*>(w1p + (size_t)k * 128);
        const float4 wb = *reinterpret_cast<const float4*>(wbp + (size_t)k * 128);
        const float4 xv4 = *reinterpret_cast<const float4*>(&xt[k][tok0]);
        const float xv[4] = {xv4.x, xv4.y, xv4.z, xv4.w};
#pragma unroll
        for (int i = 0; i < 4; ++i) {
          a1[i][0] = fmaf(xv[i], w1.x, a1[i][0]);
          a1[i][1] = fmaf(xv[i], w1.y, a1[i][1]);
          a1[i][2] = fmaf(xv[i], w1.z, a1[i][2]);
          a1[i][3] = fmaf(xv[i], w1.w, a1[i][3]);
          a2[i][0] = fmaf(xv[i], wb.x, a2[i][0]);
          a2[i][1] = fmaf(xv[i], wb.y, a2[i][1]);
          a2[i][2] = fmaf(xv[i], wb.z, a2[i][2]);
          a2[i][3] = fmaf(xv[i], wb.w, a2[i][3]);
        }
      }
    }
    __syncthreads();                   // pf writes visible

    // ---- GEMM pf-part ----
    {
      const float* wpp = Wb1 + (size_t)(512 + (c << 4)) * 128 + j0;
#pragma unroll 2
      for (int oo = 0; oo < 16; ++oo) {
        const float4 wp = *reinterpret_cast<const float4*>(wpp + (size_t)oo * 128);
        const float4 pv4 = *reinterpret_cast<const float4*>(&pf[oo][tok0]);
        const float pv[4] = {pv4.x, pv4.y, pv4.z, pv4.w};
#pragma unroll
        for (int i = 0; i < 4; ++i) {
          a2[i][0] = fmaf(pv[i], wp.x, a2[i][0]);
          a2[i][1] = fmaf(pv[i], wp.y, a2[i][1]);
          a2[i][2] = fmaf(pv[i], wp.z, a2[i][2]);
          a2[i][3] = fmaf(pv[i], wp.w, a2[i][3]);
        }
      }
    }
  }

  // ---- epilogue: relu, project, cross-jq reduce, sigmoid ----
  {
    float b1v[4], w2v[4], bbv[4], wv2[4];
#pragma unroll
    for (int jj = 0; jj < 4; ++jj) {
      b1v[jj] = b1[j0 + jj];  w2v[jj] = W2[j0 + jj];
      bbv[jj] = bb1[j0 + jj]; wv2[jj] = Wb2[j0 + jj];
    }
    const float bias2 = b2[0], biasb2 = bb2[0];
#pragma unroll
    for (int i = 0; i < 4; ++i) {
      float p1 = 0.f, p2 = 0.f;
#pragma unroll
      for (int jj = 0; jj < 4; ++jj) {
        const float h1 = a1[i][jj] + b1v[jj];
        if (h1 > 0.f) p1 = fmaf(h1, w2v[jj], p1);
        const float h2 = a2[i][jj] + bbv[jj];
        if (h2 > 0.f) p2 = fmaf(h2, wv2[jj], p2);
      }
#pragma unroll
      for (int off = 1; off < 32; off <<= 1) {
        p1 += __shfl_xor(p1, off, 64);
        p2 += __shfl_xor(p2, off, 64);
      }
      if (jq == 0) {
        const int gi = b * L_ + l0 + tok0 + i;
        const float content = 1.f / (1.f + expf(-(p1 + bias2)));
        const float bscore  = 1.f / (1.f + expf(-(p2 + biasb2)));
        signal[gi] = content * (1.f - bscore) * mask[gi];
      }
    }
  }

  // ---- e epilogue: butterfly over the 8 skk lanes of each token ----
  {
    float es = esacc;
    es += __shfl_xor(es, 1, 64);
    es += __shfl_xor(es, 2, 64);
    es += __shfl_xor(es, 4, 64);
    if ((t & 7) == 0) {
      const int gi = b * L_ + l0 + stok;
      const float m = mask[gi];
      e[gi] = m * m * es;
    }
  }
}

// ---------------------------------------------------------------------------
// Fused quantile + enforce. One block (1024 thr) per batch row.
// Radix-select rank 5733 (privatized bins), successor via <=-count + min-gt
// pass over register keys, then block-decomposed greedy chain (R4 scheme).
// ---------------------------------------------------------------------------
__device__ __forceinline__ int chain_sim(unsigned long long w, int from) {
  int last = -1;
  while (from < 64) {
    const unsigned long long m = w & (~0ull << from);
    if (m == 0ull) break;
    const int p = __ffsll(m) - 1;
    last = p;
    from = p + 4;
  }
  return last;
}

__global__ __launch_bounds__(1024) void k_select(
    const float* __restrict__ signal,
    int* __restrict__ starts, int* __restrict__ nlast, float* __restrict__ bounds)
{
  __shared__ unsigned int bins[4][256];
  __shared__ unsigned int sel_prefix;
  __shared__ int sel_rank;
  __shared__ float sh_thr;
  __shared__ unsigned int wmin[16];
  __shared__ int wcnt[16];
  __shared__ unsigned long long cw[128];
  __shared__ unsigned char nb[L_];
  __shared__ signed char tbl[128][4];
  __shared__ int st_in[128];
  __shared__ int tsum[256];
  __shared__ int offs[257];

  const int b = blockIdx.x, t = threadIdx.x;
  const int wv = t >> 6, lane = t & 63;
  const float* s = signal + b * L_;

  float val[8];
  unsigned int key[8];
#pragma unroll
  for (int i = 0; i < 8; ++i) {
    val[i] = s[(i << 10) + t];
    const unsigned int u = __float_as_uint(val[i]);
    key[i] = (u & 0x80000000u) ? ~u : (u | 0x80000000u);
  }

  // ---- radix select rank 5733 = floor(0.7*(L-1)) ----
  if (t == 0) { sel_prefix = 0u; sel_rank = 5733; }
  __syncthreads();
  for (int round = 0; round < 4; ++round) {
    reinterpret_cast<unsigned int*>(bins)[t] = 0u;
    __syncthreads();
    const unsigned int pre = sel_prefix;
    const int shift = 24 - 8 * round;
#pragma unroll
    for (int i = 0; i < 8; ++i) {
      if (round == 0 || (key[i] >> (shift + 8)) == pre)
        atomicAdd(&bins[t >> 8][(key[i] >> shift) & 255u], 1u);
    }
    __syncthreads();
    if (t < 256)
      bins[0][t] = bins[0][t] + bins[1][t] + bins[2][t] + bins[3][t];
    __syncthreads();
    if (t < 64) {
      const unsigned int c0 = bins[0][(t << 2) + 0], c1 = bins[0][(t << 2) + 1];
      const unsigned int c2 = bins[0][(t << 2) + 2], c3 = bins[0][(t << 2) + 3];
      const unsigned int lsum = c0 + c1 + c2 + c3;
      unsigned int run = lsum;
#pragma unroll
      for (int off = 1; off < 64; off <<= 1) {
        const unsigned int v = __shfl_up(run, off, 64);
        if (t >= off) run += v;
      }
      const int r = sel_rank;
      if (r >= (int)(run - lsum) && r < (int)run) {
        int rr = r - (int)(run - lsum);
        unsigned int cbin;
        if (rr < (int)c0) { cbin = 0; }
        else if (rr < (int)(c0 + c1)) { cbin = 1; rr -= (int)c0; }
        else if (rr < (int)(c0 + c1 + c2)) { cbin = 2; rr -= (int)(c0 + c1); }
        else { cbin = 3; rr -= (int)(c0 + c1 + c2); }
        sel_rank = rr;
        sel_prefix = (pre << 8) | ((unsigned int)(t << 2) | cbin);
      }
    }
    __syncthreads();
  }
  const unsigned int k0 = sel_prefix;

  // ---- successor: count <=k0 and min of keys > k0 (tie-safe) ----
  {
    int cle = 0;
    unsigned int mgt = 0xFFFFFFFFu;
#pragma unroll
    for (int i = 0; i < 8; ++i) {
      if (key[i] <= k0) ++cle;
      else mgt = min(mgt, key[i]);
    }
#pragma unroll
    for (int off = 1; off < 64; off <<= 1) {
      cle += __shfl_xor(cle, off, 64);
      mgt = min(mgt, (unsigned int)__shfl_xor((int)mgt, off, 64));
    }
    if (lane == 0) { wcnt[wv] = cle; wmin[wv] = mgt; }
    __syncthreads();
    if (t == 0) {
      int C = 0; unsigned int M = 0xFFFFFFFFu;
      for (int g = 0; g < 16; ++g) { C += wcnt[g]; M = min(M, wmin[g]); }
      const unsigned int k1 = (C >= 5735) ? k0 : M;
      const unsigned int u0 = (k0 & 0x80000000u) ? (k0 & 0x7fffffffu) : ~k0;
      const unsigned int u1 = (k1 & 0x80000000u) ? (k1 & 0x7fffffffu) : ~k1;
      const float v0 = __uint_as_float(u0);
      const float v1 = __uint_as_float(u1);
      const float g = 0.7f * 8191.0f - 5733.0f;
      sh_thr = v0 + g * (v1 - v0);
    }
    __syncthreads();
  }
  const float thr = sh_thr;

  // ---- candidate bitmap from register values ----
#pragma unroll
  for (int i = 0; i < 8; ++i) {
    const unsigned long long m = __ballot(val[i] < thr);
    if (lane == 0) cw[(i << 4) + wv] = m;
  }
  {
    const int base = t << 3;
#pragma unroll
    for (int i = 0; i < 8; ++i) nb[base + i] = 0;
  }
  __syncthreads();
  if (t == 0) cw[127] |= (1ull << 63);   // forced candidate at L-1
  __syncthreads();

  // ---- (1) per-64-block transition tables ----
  if (t < 512) {
    const int blk = t >> 2, cls = t & 3;
    tbl[blk][cls] = (signed char)chain_sim(cw[blk], cls);
  }
  __syncthreads();

  // ---- (2) serial 128-step state scan ----
  if (t == 0) {
    int st = 0;
    for (int blk = 0; blk < 128; ++blk) {
      const int bs = blk << 6;
      st_in[blk] = st;
      int pl;
      if (blk == 0) {
        pl = chain_sim(cw[0], 4);
      } else {
        int off = st + 4 - bs;
        if (off < 0) off = 0;
        pl = tbl[blk][off];
      }
      if (pl >= 0) st = bs + pl;
    }
  }
  __syncthreads();

  // ---- (3) parallel emission of acceptance + split bytes ----
  if (t < 128) {
    const int bs = t << 6;
    const unsigned long long w = cw[t];
    int st = st_in[t];
    int from = st + 4 - bs;
    if (from < 0) from = 0;
    while (from < 64) {
      const unsigned long long m = w & (~0ull << from);
      if (m == 0ull) break;
      const int p_rel = __ffsll(m) - 1;
      const int p = bs + p_rel;
      nb[p] = 1;
      const int ps = p - st;
      const int k = (ps + 15) >> 4;
      if (k > 1) {
        int sz = ps / k; if (sz < 1) sz = 1;
        for (int j = 1; j < k; ++j) nb[st + j * sz] = 1;
      }
      st = p;
      from = p_rel + 4;
    }
  }
  __syncthreads();

  // ---- prefix scan -> starts / nlast / bounds ----
  if (t < 256) {
    const int base = t << 5;
    int ls = 0;
    for (int i = 0; i < 32; ++i) ls += nb[base + i];
    tsum[t] = ls;
  }
  __syncthreads();
  if (t == 0) {
    int r = 0;
    for (int i = 0; i < 256; ++i) { offs[i] = r; r += tsum[i]; }
    offs[256] = r;
  }
  __syncthreads();
  if (t < 256) {
    const int base = t << 5;
    int run = offs[t];
    for (int i = 0; i < 32; ++i) {
      run += nb[base + i];
      if (nb[base + i]) starts[b * L_ + run] = base + i;
    }
  }
  if (t == 0) { starts[b * L_ + 0] = 0; nlast[b] = offs[256]; }
  __syncthreads();
  const int total = offs[256];
  for (int i = t; i < L_; i += 1024)
    bounds[b * L_ + i] = (i >= 1 && i <= total) ? 1.0f : 0.0f;
}

// ---------------------------------------------------------------------------
// Segment softmax-merge: one wave per segment id; dead sids write zeros.
// ---------------------------------------------------------------------------
__global__ __launch_bounds__(64) void k_merge(const float* __restrict__ x,
    const float* __restrict__ mask, const float* __restrict__ e,
    const int* __restrict__ starts, const int* __restrict__ nlast,
    float* __restrict__ merged)
{
  const int idx = blockIdx.x;
  const int b   = idx >> 13;
  const int sid = idx & (L_ - 1);
  const int n = nlast[b];
  const int lane = threadIdx.x;
  const int c0 = lane << 3;
  float* o = merged + (size_t)(b * L_ + sid) * D_ + c0;
  if (sid > n) {
    const float4 z = make_float4(0.f, 0.f, 0.f, 0.f);
    reinterpret_cast<float4*>(o)[0] = z;
    reinterpret_cast<float4*>(o)[1] = z;
    return;
  }
  const int t0 = starts[b * L_ + sid];
  const int t1 = (sid < n) ? starts[b * L_ + sid + 1] : L_;
  const float* eb = e + b * L_;

  float mx = -INFINITY;
  for (int p = t0; p < t1; ++p) mx = fmaxf(mx, eb[p]);
  float den = 0.f;
  for (int p = t0; p < t1; ++p) den += expf(eb[p] - mx);

  float acc[8] = {0,0,0,0,0,0,0,0};
  for (int p = t0; p < t1; ++p) {
    const float wn = expf(eb[p] - mx) / den;
    const float sc = wn * mask[b * L_ + p];
    const float* xr = x + ((size_t)(b * L_ + p)) * D_ + c0;
    const float4 u0 = reinterpret_cast<const float4*>(xr)[0];
    const float4 u1 = reinterpret_cast<const float4*>(xr)[1];
    acc[0] = fmaf(sc, u0.x, acc[0]); acc[1] = fmaf(sc, u0.y, acc[1]);
    acc[2] = fmaf(sc, u0.z, acc[2]); acc[3] = fmaf(sc, u0.w, acc[3]);
    acc[4] = fmaf(sc, u1.x, acc[4]); acc[5] = fmaf(sc, u1.y, acc[5]);
    acc[6] = fmaf(sc, u1.z, acc[6]); acc[7] = fmaf(sc, u1.w, acc[7]);
  }
  reinterpret_cast<float4*>(o)[0] = make_float4(acc[0], acc[1], acc[2], acc[3]);
  reinterpret_cast<float4*>(o)[1] = make_float4(acc[4], acc[5], acc[6], acc[7]);
}

// ---------------------------------------------------------------------------
extern "C" void kernel_launch(void* const* d_in, const int* in_sizes, int n_in,
                              void* d_out, int out_size, void* d_ws, size_t ws_size,
                              hipStream_t stream) {
  (void)in_sizes; (void)n_in; (void)out_size; (void)ws_size;
  const float* x    = (const float*)d_in[0];
  const float* mask = (const float*)d_in[1];
  const float* W1   = (const float*)d_in[2];
  const float* b1   = (const float*)d_in[3];
  const float* W2   = (const float*)d_in[4];
  const float* b2   = (const float*)d_in[5];
  const float* Wc   = (const float*)d_in[6];
  const float* bc   = (const float*)d_in[7];
  const float* Wb1  = (const float*)d_in[8];
  const float* bb1  = (const float*)d_in[9];
  const float* Wb2  = (const float*)d_in[10];
  const float* bb2  = (const float*)d_in[11];

  float* merged = (float*)d_out;
  float* bounds = (float*)d_out + (size_t)BL_ * D_;

  char* ws = (char*)d_ws;
  float* signal = (float*)(ws);
  float* e      = (float*)(ws + (size_t)BL_ * 4);
  int*   starts = (int*)  (ws + (size_t)BL_ * 8);
  int*   nlast  = (int*)  (ws + (size_t)BL_ * 12);

  k_signal<<<BL_ / TOK, 256, 0, stream>>>(x, mask, W1, b1, W2, b2, Wc, bc,
                                          Wb1, bb1, Wb2, bb2, signal, e);
  k_select<<<B_, 1024, 0, stream>>>(signal, starts, nlast, bounds);
  k_merge<<<BL_, 64, 0, stream>>>(x, mask, e, starts, nlast, merged);
}